// Round 1
// baseline (335.986 us; speedup 1.0000x reference)
//
#include <hip/hip_runtime.h>

#define N 8192
#define FI 256
#define FO 128

typedef short bf16x8 __attribute__((ext_vector_type(8)));
typedef float f32x4 __attribute__((ext_vector_type(4)));

static __device__ __forceinline__ unsigned short f2bf(float x) {
  unsigned int u = __builtin_bit_cast(unsigned int, x);
  u = (u + 0x7fffu + ((u >> 16) & 1u)) >> 16;
  return (unsigned short)u;
}
static __device__ __forceinline__ float lrelu(float x) {
  return x > 0.f ? x : 0.01f * x;
}

// Kernel A: h = x@W (f32 accum); write h transposed bf16 h_t[FO][N]; ha1 = h@a1, ha2 = h@a2.
__global__ __launch_bounds__(256) void k_prep(
    const float* __restrict__ x, const float* __restrict__ W, const float* __restrict__ a,
    unsigned short* __restrict__ h_t, float* __restrict__ ha1, float* __restrict__ ha2) {
  __shared__ float xs[16][256];
  __shared__ float redA[16][2], redB[16][2];
  const int t = threadIdx.x;
  const int i0 = blockIdx.x * 16;
  #pragma unroll
  for (int ii = 0; ii < 16; ++ii)
    xs[ii][t & 255] = x[(long long)(i0 + ii) * FI + t];
  __syncthreads();
  const int rg = t >> 7;     // 0..1: row group of 8
  const int f = t & 127;     // output feature
  float accs[8] = {0.f, 0.f, 0.f, 0.f, 0.f, 0.f, 0.f, 0.f};
  for (int k = 0; k < 256; ++k) {
    const float wv = W[k * FO + f];
    #pragma unroll
    for (int rr = 0; rr < 8; ++rr) accs[rr] = fmaf(xs[rg * 8 + rr][k], wv, accs[rr]);
  }
  { // h_t[f][i0 + rg*8 .. +7]
    ushort4 s0, s1;
    s0.x = f2bf(accs[0]); s0.y = f2bf(accs[1]); s0.z = f2bf(accs[2]); s0.w = f2bf(accs[3]);
    s1.x = f2bf(accs[4]); s1.y = f2bf(accs[5]); s1.z = f2bf(accs[6]); s1.w = f2bf(accs[7]);
    unsigned short* dst = h_t + (long long)f * N + i0 + rg * 8;
    *(ushort4*)dst = s0;
    *(ushort4*)(dst + 4) = s1;
  }
  const float a1f = a[f];
  const float a2f = a[FO + f];
  const int lane = t & 63;
  const int wig = (t >> 6) & 1;
  #pragma unroll
  for (int rr = 0; rr < 8; ++rr) {
    float v1 = accs[rr] * a1f;
    float v2 = accs[rr] * a2f;
    #pragma unroll
    for (int off = 32; off; off >>= 1) { v1 += __shfl_xor(v1, off); v2 += __shfl_xor(v2, off); }
    if (lane == 0) { redA[rg * 8 + rr][wig] = v1; redB[rg * 8 + rr][wig] = v2; }
  }
  __syncthreads();
  if (t < 16) {
    ha1[i0 + t] = redA[t][0] + redA[t][1];
    ha2[i0 + t] = redB[t][0] + redB[t][1];
  }
}

// Kernel B: per block = 16 rows. Pass1: stream adj once -> bitmask in LDS + masked max of ha2
// (leaky_relu monotone => m_i = LR(ha1_i + maxmask)). Pass2a: s_i. Pass2b: per 128-j tile:
// p (f32 attention store) + p->bf16 LDS + h_t tile -> LDS + mfma_16x16x32_bf16 PV.
__global__ __launch_bounds__(512, 4) void k_gat(
    const int* __restrict__ adj, const unsigned short* __restrict__ h_t,
    const float* __restrict__ ha1g, const float* __restrict__ ha2g,
    float* __restrict__ h1, float* __restrict__ attn) {
  __shared__ unsigned long long msk[16][32][4];      // 16 KB: bit l of [r][it][k] <-> j = it*256 + 4*l + k
  __shared__ unsigned short p_lds[16][136];          // padded stride 272B (16B aligned, conflict-light)
  __shared__ unsigned short ht_lds[128][136];
  __shared__ float m_sh[16], ei_sh[16], is_sh[16];

  const int t = threadIdx.x;
  const int lane = t & 63;
  const int w = t >> 6;            // wave 0..7
  const int base = blockIdx.x * 16;

  // ---------------- pass 1 ----------------
  for (int rr = 0; rr < 2; ++rr) {
    const int r = w * 2 + rr;
    const long long rowoff = (long long)(base + r) * N;
    float mloc = -3.0e38f;
    for (int it = 0; it < 32; ++it) {
      const int j0 = it * 256 + lane * 4;
      const int4 a4 = *(const int4*)(adj + rowoff + j0);
      const float4 h2 = *(const float4*)(ha2g + j0);
      const bool b0 = a4.x > 0, b1 = a4.y > 0, b2 = a4.z > 0, b3 = a4.w > 0;
      mloc = fmaxf(mloc, b0 ? h2.x : -3.0e38f);
      mloc = fmaxf(mloc, b1 ? h2.y : -3.0e38f);
      mloc = fmaxf(mloc, b2 ? h2.z : -3.0e38f);
      mloc = fmaxf(mloc, b3 ? h2.w : -3.0e38f);
      const unsigned long long q0 = __ballot(b0), q1 = __ballot(b1);
      const unsigned long long q2 = __ballot(b2), q3 = __ballot(b3);
      if (lane == 0) { msk[r][it][0] = q0; msk[r][it][1] = q1; msk[r][it][2] = q2; msk[r][it][3] = q3; }
    }
    #pragma unroll
    for (int off = 32; off; off >>= 1) mloc = fmaxf(mloc, __shfl_xor(mloc, off));
    if (lane == 0) {
      const float ei = ha1g[base + r];
      ei_sh[r] = ei;
      m_sh[r] = lrelu(ei + mloc);
    }
  }
  __syncthreads();

  // ---------------- pass 2a: denominators ----------------
  for (int rr = 0; rr < 2; ++rr) {
    const int r = w * 2 + rr;
    const float ei = ei_sh[r], m = m_sh[r];
    float sl = 0.f;
    for (int it = 0; it < 32; ++it) {
      const int j0 = it * 256 + lane * 4;
      const float4 h2 = *(const float4*)(ha2g + j0);
      const unsigned long long q0 = msk[r][it][0], q1 = msk[r][it][1];
      const unsigned long long q2 = msk[r][it][2], q3 = msk[r][it][3];
      float e;
      e = __expf(lrelu(ei + h2.x) - m); sl += ((q0 >> lane) & 1ull) ? e : 0.f;
      e = __expf(lrelu(ei + h2.y) - m); sl += ((q1 >> lane) & 1ull) ? e : 0.f;
      e = __expf(lrelu(ei + h2.z) - m); sl += ((q2 >> lane) & 1ull) ? e : 0.f;
      e = __expf(lrelu(ei + h2.w) - m); sl += ((q3 >> lane) & 1ull) ? e : 0.f;
    }
    #pragma unroll
    for (int off = 32; off; off >>= 1) sl += __shfl_xor(sl, off);
    if (lane == 0) is_sh[r] = sl > 0.f ? 1.f / sl : 0.f;
  }
  __syncthreads();

  // ---------------- pass 2b: attention writes + MFMA PV ----------------
  const int pr = t >> 5;           // row 0..15 for p-phase
  const int pjw = t & 31;          // 4 consecutive j per thread
  f32x4 acc = {0.f, 0.f, 0.f, 0.f};
  const int f0 = w * 16;           // wave's 16 output features
  const unsigned short* prow = &p_lds[lane & 15][(lane >> 4) * 8];
  const unsigned short* hrow = &ht_lds[f0 + (lane & 15)][(lane >> 4) * 8];

  for (int jt = 0; jt < 64; ++jt) {
    { // p-phase
      const int j = jt * 128 + pjw * 4;
      const int it = j >> 8;
      const int lb = (j & 255) >> 2;
      const unsigned long long q0 = msk[pr][it][0], q1 = msk[pr][it][1];
      const unsigned long long q2 = msk[pr][it][2], q3 = msk[pr][it][3];
      const float4 h2 = *(const float4*)(ha2g + j);
      const float ei = ei_sh[pr], m = m_sh[pr], is = is_sh[pr];
      const float p0 = ((q0 >> lb) & 1ull) ? __expf(lrelu(ei + h2.x) - m) * is : 0.f;
      const float p1 = ((q1 >> lb) & 1ull) ? __expf(lrelu(ei + h2.y) - m) * is : 0.f;
      const float p2 = ((q2 >> lb) & 1ull) ? __expf(lrelu(ei + h2.z) - m) * is : 0.f;
      const float p3 = ((q3 >> lb) & 1ull) ? __expf(lrelu(ei + h2.w) - m) * is : 0.f;
      *(float4*)(attn + (long long)(base + pr) * N + j) = make_float4(p0, p1, p2, p3);
      ushort4 pb;
      pb.x = f2bf(p0); pb.y = f2bf(p1); pb.z = f2bf(p2); pb.w = f2bf(p3);
      *(ushort4*)&p_lds[pr][pjw * 4] = pb;
    }
    { // h_t tile copy: [128 f][128 j] bf16, linear global -> padded LDS
      #pragma unroll
      for (int i2 = 0; i2 < 4; ++i2) {
        const int flat = i2 * 512 + t;
        const int fr = flat >> 4;
        const int c = flat & 15;
        const int4 v = *(const int4*)(h_t + (long long)fr * N + jt * 128 + c * 8);
        *(int4*)&ht_lds[fr][c * 8] = v;
      }
    }
    __syncthreads();
    #pragma unroll
    for (int ks = 0; ks < 4; ++ks) {  // K = 128 per tile, 32 per mfma
      const bf16x8 av = *(const bf16x8*)(prow + ks * 32);
      const bf16x8 bv = *(const bf16x8*)(hrow + ks * 32);
      acc = __builtin_amdgcn_mfma_f32_16x16x32_bf16(av, bv, acc, 0, 0, 0);
    }
    __syncthreads();
  }
  { // epilogue: D[row=(l>>4)*4+reg][col=l&15], elu
    const int rbase = (lane >> 4) * 4;
    const int col = lane & 15;
    #pragma unroll
    for (int rgi = 0; rgi < 4; ++rgi) {
      float v = acc[rgi];
      v = v > 0.f ? v : __expf(v) - 1.f;
      h1[(long long)(base + rbase + rgi) * FO + f0 + col] = v;
    }
  }
}

extern "C" void kernel_launch(void* const* d_in, const int* in_sizes, int n_in,
                              void* d_out, int out_size, void* d_ws, size_t ws_size,
                              hipStream_t stream) {
  const float* x = (const float*)d_in[0];
  const int* adj = (const int*)d_in[1];
  const float* W = (const float*)d_in[2];
  const float* a = (const float*)d_in[3];
  float* h1 = (float*)d_out;
  float* attn = (float*)d_out + (size_t)N * FO;
  unsigned short* h_t = (unsigned short*)d_ws;                       // 2 MB
  float* ha1 = (float*)((char*)d_ws + (size_t)FO * N * 2);           // 32 KB
  float* ha2 = ha1 + N;                                              // 32 KB
  k_prep<<<N / 16, 256, 0, stream>>>(x, W, a, h_t, ha1, ha2);
  k_gat<<<N / 16, 512, 0, stream>>>(adj, h_t, ha1, ha2, h1, attn);
}

// Round 3
// 237.053 us; speedup vs baseline: 1.4173x; 1.4173x over previous
//
#include <hip/hip_runtime.h>

#define N 8192
#define FI 256
#define FO 128

typedef short bf16x8 __attribute__((ext_vector_type(8)));
typedef float f32x4 __attribute__((ext_vector_type(4)));
typedef unsigned short u16x4 __attribute__((ext_vector_type(4)));
typedef unsigned long long u64;
typedef u64 u64x2 __attribute__((ext_vector_type(2)));

static __device__ __forceinline__ unsigned short f2bf(float x) {
  unsigned int u = __builtin_bit_cast(unsigned int, x);
  u = (u + 0x7fffu + ((u >> 16) & 1u)) >> 16;
  return (unsigned short)u;
}
static __device__ __forceinline__ float lrelu(float x) {
  return fmaxf(x, 0.01f * x);
}

// Kernel A: h = x@W (f32 accum); write h transposed bf16 h_t[FO][N]; ha1 = h@a1, ha2 = h@a2.
__global__ __launch_bounds__(256) void k_prep(
    const float* __restrict__ x, const float* __restrict__ W, const float* __restrict__ a,
    unsigned short* __restrict__ h_t, float* __restrict__ ha1, float* __restrict__ ha2) {
  __shared__ float xs[16][256];
  __shared__ float redA[16][2], redB[16][2];
  const int t = threadIdx.x;
  const int i0 = blockIdx.x * 16;
  #pragma unroll
  for (int ii = 0; ii < 16; ++ii)
    xs[ii][t & 255] = x[(long long)(i0 + ii) * FI + t];
  __syncthreads();
  const int rg = t >> 7;
  const int f = t & 127;
  float accs[8] = {0.f, 0.f, 0.f, 0.f, 0.f, 0.f, 0.f, 0.f};
  for (int k = 0; k < 256; ++k) {
    const float wv = W[k * FO + f];
    #pragma unroll
    for (int rr = 0; rr < 8; ++rr) accs[rr] = fmaf(xs[rg * 8 + rr][k], wv, accs[rr]);
  }
  {
    ushort4 s0, s1;
    s0.x = f2bf(accs[0]); s0.y = f2bf(accs[1]); s0.z = f2bf(accs[2]); s0.w = f2bf(accs[3]);
    s1.x = f2bf(accs[4]); s1.y = f2bf(accs[5]); s1.z = f2bf(accs[6]); s1.w = f2bf(accs[7]);
    unsigned short* dst = h_t + (long long)f * N + i0 + rg * 8;
    *(ushort4*)dst = s0;
    *(ushort4*)(dst + 4) = s1;
  }
  const float a1f = a[f];
  const float a2f = a[FO + f];
  const int lane = t & 63;
  const int wig = (t >> 6) & 1;
  #pragma unroll
  for (int rr = 0; rr < 8; ++rr) {
    float v1 = accs[rr] * a1f;
    float v2 = accs[rr] * a2f;
    #pragma unroll
    for (int off = 32; off; off >>= 1) { v1 += __shfl_xor(v1, off); v2 += __shfl_xor(v2, off); }
    if (lane == 0) { redA[rg * 8 + rr][wig] = v1; redB[rg * 8 + rr][wig] = v2; }
  }
  __syncthreads();
  if (t < 16) {
    ha1[i0 + t] = redA[t][0] + redA[t][1];
    ha2[i0 + t] = redB[t][0] + redB[t][1];
  }
}

// Kernel B: one wave per row. Stream adj once: ballot -> bitmask (global ws), and
// online-softmax (m, s) over masked e = lrelu(ei + ha2[j]). Writes lse = m + log(s).
template <int WM>
__global__ __launch_bounds__(256) void k_mask(
    const int* __restrict__ adj, const float* __restrict__ ha1g, const float* __restrict__ ha2g,
    u64* __restrict__ msk, float* __restrict__ lse_row) {
  const int t = threadIdx.x;
  const int lane = t & 63;
  const int row = blockIdx.x * 4 + (t >> 6);
  const float ei = ha1g[row];
  const int* __restrict__ arow = adj + (size_t)row * N;
  u64* __restrict__ mrow = msk + (size_t)row * 128;
  float m = -3.0e38f, s = 0.f;
  for (int it = 0; it < 32; ++it) {
    const int j0 = it * 256 + lane * 4;
    const int4 a4 = *(const int4*)(arow + j0);
    const float4 h2 = *(const float4*)(ha2g + j0);
    const bool b0 = a4.x > 0, b1 = a4.y > 0, b2 = a4.z > 0, b3 = a4.w > 0;
    #define ONLINE(bb, vv) { \
      const float t0 = ei + (vv); \
      const float e = lrelu(t0); \
      const float mn = (bb) ? fmaxf(m, e) : m; \
      s = fmaf(s, __expf(m - mn), (bb) ? __expf(e - mn) : 0.f); \
      m = mn; }
    ONLINE(b0, h2.x) ONLINE(b1, h2.y) ONLINE(b2, h2.z) ONLINE(b3, h2.w)
    #undef ONLINE
    if (WM) {
      const u64 q0 = __ballot(b0), q1 = __ballot(b1);
      const u64 q2 = __ballot(b2), q3 = __ballot(b3);
      if (lane == 0) {
        u64x2 v01 = {q0, q1}, v23 = {q2, q3};
        *(u64x2*)(mrow + it * 4) = v01;
        *(u64x2*)(mrow + it * 4 + 2) = v23;
      }
    }
  }
  #pragma unroll
  for (int off = 32; off; off >>= 1) {
    const float mo = __shfl_xor(m, off);
    const float so = __shfl_xor(s, off);
    const float mn = fmaxf(m, mo);
    s = s * __expf(m - mn) + so * __expf(mo - mn);
    m = mn;
  }
  if (lane == 0) lse_row[row] = (s > 0.f) ? (m + __logf(s)) : 3.0e38f;
}

// Kernel C: 16 rows/block, 8 waves. Per 128-j tile: compute p (exp from mask+ha2+lse),
// nontemporal f32 attn store, p->bf16 LDS (double-buffered, ONE barrier/iter); B-operand
// (h_t) loads straight global(L2)->VGPR, register double-buffered. mfma 16x16x32 PV.
template <int UA>
__global__ __launch_bounds__(512) void k_pv(
    const int* __restrict__ adj, const u64* __restrict__ msk,
    const unsigned short* __restrict__ h_t, const float* __restrict__ ha1g,
    const float* __restrict__ ha2g, const float* __restrict__ lse_row,
    float* __restrict__ h1, float* __restrict__ attn) {
  __shared__ unsigned short p_lds[2][16][136];
  const int t = threadIdx.x;
  const int lane = t & 63;
  const int w = t >> 6;
  const int base = blockIdx.x * 16;
  const int pr = t >> 5;           // p-compute row 0..15
  const int pjw = t & 31;          // 4 consecutive j per thread
  const float ei = ha1g[base + pr];
  const float nls = lse_row[base + pr];
  const u64* __restrict__ mrow = msk + (size_t)(base + pr) * 128;
  const int* __restrict__ arow = adj + (size_t)(base + pr) * N;
  float* __restrict__ atrow = attn + (size_t)(base + pr) * N;

  const int f0 = w * 16;
  const unsigned short* __restrict__ hbase =
      h_t + (size_t)(f0 + (lane & 15)) * N + (lane >> 4) * 8;
  // A-fragment base: row (lane&15), k-offset (lane>>4)*8 — row term included HERE ONLY.
  const unsigned short* pfrag0 = &p_lds[0][lane & 15][(lane >> 4) * 8];

  f32x4 acc = {0.f, 0.f, 0.f, 0.f};

  auto compute_p = [&](int jt) {
    const int j = jt * 128 + pjw * 4;
    bool b0, b1, b2, b3;
    if constexpr (UA) {
      const int4 a4 = *(const int4*)(arow + j);
      b0 = a4.x > 0; b1 = a4.y > 0; b2 = a4.z > 0; b3 = a4.w > 0;
    } else {
      const int it = j >> 8;
      const int l = (j >> 2) & 63;
      const u64x2 qa = *(const u64x2*)(mrow + it * 4);
      const u64x2 qb = *(const u64x2*)(mrow + it * 4 + 2);
      b0 = (qa.x >> l) & 1; b1 = (qa.y >> l) & 1;
      b2 = (qb.x >> l) & 1; b3 = (qb.y >> l) & 1;
    }
    const float4 h2 = *(const float4*)(ha2g + j);
    const float p0 = b0 ? __expf(lrelu(ei + h2.x) - nls) : 0.f;
    const float p1 = b1 ? __expf(lrelu(ei + h2.y) - nls) : 0.f;
    const float p2 = b2 ? __expf(lrelu(ei + h2.z) - nls) : 0.f;
    const float p3 = b3 ? __expf(lrelu(ei + h2.w) - nls) : 0.f;
    f32x4 pv = {p0, p1, p2, p3};
    __builtin_nontemporal_store(pv, (f32x4*)(atrow + j));
    u16x4 pb = {f2bf(p0), f2bf(p1), f2bf(p2), f2bf(p3)};
    *(u16x4*)&p_lds[(jt & 1)][pr][pjw * 4] = pb;
  };

  bf16x8 hA[4], hB[4];
  compute_p(0);
  #pragma unroll
  for (int ks = 0; ks < 4; ++ks) hA[ks] = *(const bf16x8*)(hbase + ks * 32);
  __syncthreads();

  for (int jt = 0; jt < 64; ++jt) {
    if (jt < 63) {
      compute_p(jt + 1);
      #pragma unroll
      for (int ks = 0; ks < 4; ++ks)
        hB[ks] = *(const bf16x8*)(hbase + (jt + 1) * 128 + ks * 32);
    }
    const unsigned short* pf = pfrag0 + (jt & 1) * (16 * 136);
    #pragma unroll
    for (int ks = 0; ks < 4; ++ks) {
      const bf16x8 av = *(const bf16x8*)(pf + ks * 32);
      acc = __builtin_amdgcn_mfma_f32_16x16x32_bf16(av, hA[ks], acc, 0, 0, 0);
    }
    if (jt < 63) {
      __syncthreads();
      #pragma unroll
      for (int ks = 0; ks < 4; ++ks) hA[ks] = hB[ks];
    }
  }
  { // epilogue: D[row=(l>>4)*4+reg][col=l&15], elu
    const int rbase = (lane >> 4) * 4;
    const int col = lane & 15;
    #pragma unroll
    for (int rgi = 0; rgi < 4; ++rgi) {
      float v = acc[rgi];
      v = v > 0.f ? v : __expf(v) - 1.f;
      h1[(long long)(base + rbase + rgi) * FO + f0 + col] = v;
    }
  }
}

extern "C" void kernel_launch(void* const* d_in, const int* in_sizes, int n_in,
                              void* d_out, int out_size, void* d_ws, size_t ws_size,
                              hipStream_t stream) {
  const float* x = (const float*)d_in[0];
  const int* adj = (const int*)d_in[1];
  const float* W = (const float*)d_in[2];
  const float* a = (const float*)d_in[3];
  float* h1 = (float*)d_out;
  float* attn = (float*)d_out + (size_t)N * FO;

  char* wsb = (char*)d_ws;
  unsigned short* h_t = (unsigned short*)wsb;                       // 2 MB
  float* ha1 = (float*)(wsb + (size_t)FO * N * 2);                  // 32 KB
  float* ha2 = ha1 + N;                                             // 32 KB
  float* lse = ha2 + N;                                             // 32 KB
  const size_t msk_off = (size_t)FO * N * 2 + 3 * (size_t)N * 4;    // 2,195,456
  u64* msk = (u64*)(wsb + msk_off);                                 // 8 MB
  const size_t need = msk_off + (size_t)N * 128 * 8;

  k_prep<<<N / 16, 256, 0, stream>>>(x, W, a, h_t, ha1, ha2);
  if (ws_size >= need) {
    k_mask<1><<<N / 4, 256, 0, stream>>>(adj, ha1, ha2, msk, lse);
    k_pv<0><<<N / 16, 512, 0, stream>>>(adj, msk, h_t, ha1, ha2, lse, h1, attn);
  } else {
    k_mask<0><<<N / 4, 256, 0, stream>>>(adj, ha1, ha2, msk, lse);
    k_pv<1><<<N / 16, 512, 0, stream>>>(adj, msk, h_t, ha1, ha2, lse, h1, attn);
  }
}